// Round 7
// baseline (95.378 us; speedup 1.0000x reference)
//
#include <hip/hip_runtime.h>

// loss = 2*0.5 * dot(colsum(a), colsum(b)), a,b: (16384, 512) fp32.
// Memory-bound. dur_us includes ~75-85 us of harness reset (256 MiB ws
// poison fill ~42 us + 134 MB input restore + out poison + gaps) — fixed.
// R6 (94.5 us, best): plain loads beat nontemporal by 6 us because the
// harness input-restore leaves the inputs L2/LLC-resident.
// R5's single-dispatch release/acquire fusion REGRESSED (41 us kernel) —
// 512 agent-scope L2 writebacks + 8K spinning acquire loads; the 2-kernel
// split gets coherence free at the dispatch boundary.
// R7 = R6 + vectorized stage-2 (float4 loads, 4x fewer load insts).

#define ROWS  16384
#define COLS  512
#define PB    512                   // stage-1 blocks == partial rows
#define NTHR  256
#define NT    (PB * NTHR)           // 131,072 float4 stride -> 16 iters/thread

typedef float vfloat4 __attribute__((ext_vector_type(4)));

// ws: pa[512][128] vfloat4 (1 MB), pb[512][128] vfloat4 (1 MB)

__global__ __launch_bounds__(NTHR) void colsum_partial(
        const vfloat4* __restrict__ a, const vfloat4* __restrict__ b,
        vfloat4* __restrict__ pa, vfloat4* __restrict__ pb,
        float* __restrict__ out) {
    const int tid = threadIdx.x;
    const int g0  = blockIdx.x * NTHR + tid;

    if (blockIdx.x == 0 && tid == 0) out[0] = 0.0f;  // for stage-2 atomics

    vfloat4 sa = (vfloat4)(0.f);
    vfloat4 sb = (vfloat4)(0.f);

    // stride NT is a multiple of 128 -> each thread's 4-column group is fixed
#pragma unroll
    for (int i = 0; i < 16; ++i) {
        sa += a[g0 + i * NT];
        sb += b[g0 + i * NT];
    }

    // threads t and t+128 hold the same 4-column group -> fold 256->128
    __shared__ vfloat4 la[128];
    __shared__ vfloat4 lb[128];
    if (tid >= 128) { la[tid - 128] = sa; lb[tid - 128] = sb; }
    __syncthreads();
    if (tid < 128) {
        sa += la[tid];
        sb += lb[tid];
        pa[blockIdx.x * 128 + tid] = sa;   // coalesced 16B store
        pb[blockIdx.x * 128 + tid] = sb;
    }
}

// 32 blocks x 256 threads; block b owns float4-cols 4b..4b+3 (cols 16b..16b+15).
// thread t: c4 = 4b + (t&3), row-class rc = t>>2 (64 classes over 512 rows,
// 8 float4 loads each). Each 4-lane cluster reads a contiguous 64 B segment.
__global__ __launch_bounds__(NTHR) void reduce_dot(
        const vfloat4* __restrict__ pa, const vfloat4* __restrict__ pb,
        float* __restrict__ out) {
    const int t  = threadIdx.x;
    const int c4 = blockIdx.x * 4 + (t & 3);
    const int rc = t >> 2;

    vfloat4 va = (vfloat4)(0.f);
    vfloat4 vb = (vfloat4)(0.f);
#pragma unroll
    for (int k = 0; k < 8; ++k) {
        const int r = rc + 64 * k;
        va += pa[r * 128 + c4];
        vb += pb[r * 128 + c4];
    }
    // fold the wave's 16 row-classes (lane bits 2..5)
#pragma unroll
    for (int off = 4; off <= 32; off <<= 1) {
        va.x += __shfl_xor(va.x, off, 64); va.y += __shfl_xor(va.y, off, 64);
        va.z += __shfl_xor(va.z, off, 64); va.w += __shfl_xor(va.w, off, 64);
        vb.x += __shfl_xor(vb.x, off, 64); vb.y += __shfl_xor(vb.y, off, 64);
        vb.z += __shfl_xor(vb.z, off, 64); vb.w += __shfl_xor(vb.w, off, 64);
    }

    __shared__ vfloat4 fa[4][4];
    __shared__ vfloat4 fb[4][4];
    const int wave = t >> 6, lane = t & 63;
    if (lane < 4) { fa[wave][lane] = va; fb[wave][lane] = vb; }
    __syncthreads();
    if (t < 4) {
        vfloat4 ca = fa[0][t] + fa[1][t] + fa[2][t] + fa[3][t];
        vfloat4 cb = fb[0][t] + fb[1][t] + fb[2][t] + fb[3][t];
        vfloat4 p4 = ca * cb;                  // per-column products
        float p = p4.x + p4.y + p4.z + p4.w;
        p += __shfl_xor(p, 1, 64);
        p += __shfl_xor(p, 2, 64);
        if (t == 0) atomicAdd(out, p);         // 2*lambd = 1.0
    }
}

extern "C" void kernel_launch(void* const* d_in, const int* in_sizes, int n_in,
                              void* d_out, int out_size, void* d_ws, size_t ws_size,
                              hipStream_t stream) {
    const vfloat4* a = (const vfloat4*)d_in[0];
    const vfloat4* b = (const vfloat4*)d_in[1];
    float* out = (float*)d_out;

    vfloat4* pa = (vfloat4*)d_ws;               // [512][128] vfloat4
    vfloat4* pb = pa + PB * (COLS / 4);         // [512][128] vfloat4

    colsum_partial<<<PB, NTHR, 0, stream>>>(a, b, pa, pb, out);
    reduce_dot<<<COLS / 16, NTHR, 0, stream>>>(pa, pb, out);
}